// Round 8
// baseline (1371.997 us; speedup 1.0000x reference)
//
#include <hip/hip_runtime.h>
#include <hip/hip_bf16.h>
#include <stdint.h>

#define TOKENS 8192
#define DIN    4096
#define DOUT   16384

#define BM 256
#define BN 256
#define BKT 64                 // K per tile
#define NT (DIN / BKT)         // 64 K-tiles
#define NJ (NT / 2)            // 32 iterations, 2 tiles each

typedef short s16x8 __attribute__((ext_vector_type(8)));
typedef float f32x4 __attribute__((ext_vector_type(4)));

#define AS1 __attribute__((address_space(1)))
#define AS3 __attribute__((address_space(3)))
#define VMCNT(n)  asm volatile("s_waitcnt vmcnt(" #n ")" ::: "memory")
#define LGKM0()   asm volatile("s_waitcnt lgkmcnt(0)" ::: "memory")
#define LGKM8()   asm volatile("s_waitcnt lgkmcnt(8)" ::: "memory")
#define SCHEDB()  __builtin_amdgcn_sched_barrier(0)
#define BAR()     __builtin_amdgcn_s_barrier()
#define PRIO1()   __builtin_amdgcn_s_setprio(1)
#define PRIO0()   __builtin_amdgcn_s_setprio(0)

__device__ __forceinline__ unsigned short f2bf(float f) {
  unsigned int u = __float_as_uint(f);
  u += 0x7fffu + ((u >> 16) & 1u);   // round-to-nearest-even
  return (unsigned short)(u >> 16);
}

// -------- Kernel 1: LayerNorm fp32 -> bf16
__global__ __launch_bounds__(256) void ln_kernel(const float* __restrict__ x,
                                                 unsigned short* __restrict__ xn) {
  const int row = blockIdx.x;
  const float4* xr = reinterpret_cast<const float4*>(x + (size_t)row * DIN);
  float4 v[4];
  float sum = 0.f, ssq = 0.f;
#pragma unroll
  for (int i = 0; i < 4; ++i) {
    v[i] = xr[threadIdx.x + i * 256];
    sum += v[i].x + v[i].y + v[i].z + v[i].w;
    ssq += v[i].x * v[i].x + v[i].y * v[i].y + v[i].z * v[i].z + v[i].w * v[i].w;
  }
#pragma unroll
  for (int off = 32; off > 0; off >>= 1) {
    sum += __shfl_xor(sum, off, 64);
    ssq += __shfl_xor(ssq, off, 64);
  }
  __shared__ float red[8];
  const int wid = threadIdx.x >> 6;
  if ((threadIdx.x & 63) == 0) { red[wid] = sum; red[wid + 4] = ssq; }
  __syncthreads();
  sum = red[0] + red[1] + red[2] + red[3];
  ssq = red[4] + red[5] + red[6] + red[7];
  const float mean = sum * (1.f / DIN);
  const float var  = ssq * (1.f / DIN) - mean * mean;
  const float rs   = rsqrtf(var + 1e-5f);
  ushort4* xo = reinterpret_cast<ushort4*>(xn + (size_t)row * DIN);
#pragma unroll
  for (int i = 0; i < 4; ++i) {
    ushort4 o;
    o.x = f2bf((v[i].x - mean) * rs);
    o.y = f2bf((v[i].y - mean) * rs);
    o.z = f2bf((v[i].z - mean) * rs);
    o.w = f2bf((v[i].w - mean) * rs);
    xo[threadIdx.x + i * 256] = o;
  }
}

// -------- Kernel 2: W fp32 -> bf16
__global__ __launch_bounds__(256) void cvt_kernel(const float* __restrict__ W,
                                                  unsigned short* __restrict__ Wb) {
  const size_t i = (size_t)blockIdx.x * 256 + threadIdx.x;
  float4 v = reinterpret_cast<const float4*>(W)[i];
  ushort4 o;
  o.x = f2bf(v.x); o.y = f2bf(v.y); o.z = f2bf(v.z); o.w = f2bf(v.w);
  reinterpret_cast<ushort4*>(Wb)[i] = o;
}

// -------- Kernel 3: faithful m201-template port.
// 256x256, BK=64, 8 waves 2x4, dbuf LDS. Per phase: {ds_read subtile
// (12/4/8/0) || stage quarters -> BAR -> lgkmcnt(0)+sched_barrier ->
// setprio(1) 16 MFMA setprio(0) -> BAR}. vmcnt(4) ONLY at ph4/ph8 tops.
// Stage schedule [0,2,2,4,0,2,2,4]; ledger-verified: every quarter
// confirmed (oldest-first vmcnt drain) 1+ phase before first read with
// 5-7-phase issue lead; every stage >=1 closing-barrier after the
// overwritten region's last read. Involution swizzle (0 conflicts).
__global__ __launch_bounds__(512, 2) void gemm_sig(const unsigned short* __restrict__ A,
                                                   const unsigned short* __restrict__ B,
                                                   float* __restrict__ C) {
  __shared__ unsigned short Asl[2 * 256 * 64];  // 64 KB
  __shared__ unsigned short Bsl[2 * 256 * 64];  // 64 KB

  const int bid = blockIdx.x;
  const int cpx = gridDim.x >> 3;
  const int swz = (bid & 7) * cpx + (bid >> 3);
  const int bm = swz & 31;      // TOKENS/BM = 32
  const int bn = swz >> 5;      // DOUT/BN  = 64

  const int tid  = threadIdx.x;
  const int wid  = tid >> 6;
  const int lane = tid & 63;
  const int wr = wid >> 2, wc = wid & 3;

  const unsigned short* gA = A + (size_t)bm * BM * DIN;
  const unsigned short* gB = B + (size_t)bn * BN * DIN;

  // Staging: 1 gload = 512 lanes x 16B = 8 KB = 64 rows. Lane l of wave wid
  // writes LDS row wid*8+(l>>3), slot l&7 (linear dest); fetches global slot
  // (l&7)^(l>>3) (involution swizzle keyed on row&7; 0 conflicts, validated).
  const int l8 = lane >> 3, l7 = lane & 7;
  const int csw = l7 ^ l8;
  const unsigned short* sA = gA + (size_t)(wid * 8 + l8) * DIN + csw * 8;
  const unsigned short* sB = gB + (size_t)(wid * 8 + l8) * DIN + csw * 8;
  const int dOfs = wid * 512;   // ushort units

#define STG_Aq(p, q, kt) __builtin_amdgcn_global_load_lds( \
    (const AS1 void*)(sA + (size_t)(q) * 64 * DIN + (size_t)(kt) * BKT), \
    (AS3 void*)(Asl + ((p) * 256 + (q) * 64) * 64 + dOfs), 16, 0, 0)
#define STG_Bq(p, q, kt) __builtin_amdgcn_global_load_lds( \
    (const AS1 void*)(sB + (size_t)(q) * 64 * DIN + (size_t)(kt) * BKT), \
    (AS3 void*)(Bsl + ((p) * 256 + (q) * 64) * 64 + dOfs), 16, 0, 0)

  // Read side: logical k-slot qk = (lane>>4)+4*kh stored at slot qk^(row&7);
  // row&7 == lane&7 here (row bases are multiples of 8).
  int aO[8], bO[4];
#pragma unroll
  for (int m = 0; m < 8; ++m) aO[m] = (wr * 128 + m * 16 + (lane & 15)) * 64;
#pragma unroll
  for (int n = 0; n < 4; ++n) bO[n] = (wc * 64 + n * 16 + (lane & 15)) * 64;
  const int slt0 = ((lane >> 4) ^ l7) * 8;
  const int slt1 = (((lane >> 4) + 4) ^ l7) * 8;

  s16x8 a0[4], a1[4], b0k0[2], b0k1[2], b1k0[2], b1k1[2];
  f32x4 acc[8][4] = {};

#define RD_A2(p, mb4) do { _Pragma("unroll") for (int mm = 0; mm < 4; ++mm) { \
    const unsigned short* _b = Asl + (p) * 16384 + aO[(mb4) + mm]; \
    a0[mm] = *reinterpret_cast<const s16x8*>(_b + slt0); \
    a1[mm] = *reinterpret_cast<const s16x8*>(_b + slt1); } } while (0)
#define RD_B2(p, nb2, d0, d1) do { _Pragma("unroll") for (int nn = 0; nn < 2; ++nn) { \
    const unsigned short* _b = Bsl + (p) * 16384 + bO[(nb2) + nn]; \
    d0[nn] = *reinterpret_cast<const s16x8*>(_b + slt0); \
    d1[nn] = *reinterpret_cast<const s16x8*>(_b + slt1); } } while (0)
#define MM8(mb4, nb2, bk0, bk1) do { _Pragma("unroll") for (int mm = 0; mm < 4; ++mm) \
    _Pragma("unroll") for (int nn = 0; nn < 2; ++nn) { \
      acc[(mb4) + mm][(nb2) + nn] = __builtin_amdgcn_mfma_f32_16x16x32_bf16(a0[mm], bk0[nn], acc[(mb4) + mm][(nb2) + nn], 0, 0, 0); \
      acc[(mb4) + mm][(nb2) + nn] = __builtin_amdgcn_mfma_f32_16x16x32_bf16(a1[mm], bk1[nn], acc[(mb4) + mm][(nb2) + nn], 0, 0, 0); } } while (0)

  // Prologue: t0 all 8 quarters, then t1 all 8. vmcnt(8) -> t0 landed.
  STG_Aq(0, 0, 0); STG_Aq(0, 1, 0); STG_Aq(0, 2, 0); STG_Aq(0, 3, 0);
  STG_Bq(0, 0, 0); STG_Bq(0, 1, 0); STG_Bq(0, 2, 0); STG_Bq(0, 3, 0);
  STG_Aq(1, 0, 1); STG_Aq(1, 2, 1);
  STG_Bq(1, 0, 1); STG_Bq(1, 1, 1); STG_Bq(1, 2, 1); STG_Bq(1, 3, 1);
  STG_Aq(1, 1, 1); STG_Aq(1, 3, 1);
  VMCNT(8); BAR();

  for (int j = 0; j < NJ - 1; ++j) {
    const int t2 = 2 * j + 2, t3 = 2 * j + 3;
    // ph1: 12 reads (A m0-3 both kh, B n0-1 both kh); no stage
    RD_A2(0, 0); RD_B2(0, 0, b0k0, b0k1);
    LGKM8();
    BAR(); LGKM0(); SCHEDB();
    PRIO1(); MM8(0, 0, b0k0, b0k1); PRIO0(); BAR();
    // ph2: 4 reads (B n2-3); stage A0'q0,q2
    RD_B2(0, 2, b1k0, b1k1);
    STG_Aq(0, 0, t2); STG_Aq(0, 2, t2);
    BAR(); LGKM0(); SCHEDB();
    PRIO1(); MM8(0, 2, b1k0, b1k1); PRIO0(); BAR();
    // ph3: 8 reads (A m4-7); stage B0'q0,q1
    RD_A2(0, 4);
    STG_Bq(0, 0, t2); STG_Bq(0, 1, t2);
    BAR(); LGKM0(); SCHEDB();
    PRIO1(); MM8(4, 0, b0k0, b0k1); PRIO0(); BAR();
    // ph4: vmcnt checkpoint; 0 reads; stage B0'q2,q3 + A0'q1,q3
    VMCNT(4);
    STG_Bq(0, 2, t2); STG_Bq(0, 3, t2); STG_Aq(0, 1, t2); STG_Aq(0, 3, t2);
    BAR();
    PRIO1(); MM8(4, 2, b1k0, b1k1); PRIO0(); BAR();
    // ph5: buf1; 12 reads; no stage
    RD_A2(1, 0); RD_B2(1, 0, b0k0, b0k1);
    LGKM8();
    BAR(); LGKM0(); SCHEDB();
    PRIO1(); MM8(0, 0, b0k0, b0k1); PRIO0(); BAR();
    // ph6: 4 reads; stage A1'q0,q2
    RD_B2(1, 2, b1k0, b1k1);
    STG_Aq(1, 0, t3); STG_Aq(1, 2, t3);
    BAR(); LGKM0(); SCHEDB();
    PRIO1(); MM8(0, 2, b1k0, b1k1); PRIO0(); BAR();
    // ph7: 8 reads; stage B1'q0,q1
    RD_A2(1, 4);
    STG_Bq(1, 0, t3); STG_Bq(1, 1, t3);
    BAR(); LGKM0(); SCHEDB();
    PRIO1(); MM8(4, 0, b0k0, b0k1); PRIO0(); BAR();
    // ph8: vmcnt checkpoint; 0 reads; stage B1'q2,q3 + A1'q1,q3
    VMCNT(4);
    STG_Bq(1, 2, t3); STG_Bq(1, 3, t3); STG_Aq(1, 1, t3); STG_Aq(1, 3, t3);
    BAR();
    PRIO1(); MM8(4, 2, b1k0, b1k1); PRIO0(); BAR();
  }

  // Tail iteration (t0 = NT-2, t1 = NT-1): no stages; drain at ph4.
  {
    RD_A2(0, 0); RD_B2(0, 0, b0k0, b0k1);
    LGKM8();
    BAR(); LGKM0(); SCHEDB();
    PRIO1(); MM8(0, 0, b0k0, b0k1); PRIO0(); BAR();
    RD_B2(0, 2, b1k0, b1k1);
    BAR(); LGKM0(); SCHEDB();
    PRIO1(); MM8(0, 2, b1k0, b1k1); PRIO0(); BAR();
    RD_A2(0, 4);
    BAR(); LGKM0(); SCHEDB();
    PRIO1(); MM8(4, 0, b0k0, b0k1); PRIO0(); BAR();
    VMCNT(0);
    BAR();
    PRIO1(); MM8(4, 2, b1k0, b1k1); PRIO0(); BAR();
    RD_A2(1, 0); RD_B2(1, 0, b0k0, b0k1);
    LGKM8();
    BAR(); LGKM0(); SCHEDB();
    PRIO1(); MM8(0, 0, b0k0, b0k1); PRIO0(); BAR();
    RD_B2(1, 2, b1k0, b1k1);
    BAR(); LGKM0(); SCHEDB();
    PRIO1(); MM8(0, 2, b1k0, b1k1); PRIO0(); BAR();
    RD_A2(1, 4);
    BAR(); LGKM0(); SCHEDB();
    PRIO1(); MM8(4, 0, b0k0, b0k1); PRIO0(); BAR();
    PRIO1(); MM8(4, 2, b1k0, b1k1); PRIO0();
  }

#undef STG_Aq
#undef STG_Bq
#undef RD_A2
#undef RD_B2
#undef MM8

  // Epilogue: C/D layout col = lane&15, row = (lane>>4)*4 + j
  const int crow0 = bm * BM + wr * 128 + (lane >> 4) * 4;
  const int ccol0 = bn * BN + wc * 64 + (lane & 15);
#pragma unroll
  for (int m = 0; m < 8; ++m)
#pragma unroll
    for (int n = 0; n < 4; ++n)
#pragma unroll
      for (int jj = 0; jj < 4; ++jj) {
        const float v = acc[m][n][jj];
        C[(size_t)(crow0 + m * 16 + jj) * DOUT + (ccol0 + n * 16)] = 1.f / (1.f + __expf(-v));
      }
}

extern "C" void kernel_launch(void* const* d_in, const int* in_sizes, int n_in,
                              void* d_out, int out_size, void* d_ws, size_t ws_size,
                              hipStream_t stream) {
  const float* x = (const float*)d_in[0];
  const float* W = (const float*)d_in[1];
  float* out = (float*)d_out;

  unsigned short* xn = (unsigned short*)d_ws;                    // 64 MiB
  unsigned short* Wb = xn + (size_t)TOKENS * DIN;                // 128 MiB

  ln_kernel<<<TOKENS, 256, 0, stream>>>(x, xn);
  cvt_kernel<<<((size_t)DOUT * DIN) / 1024, 256, 0, stream>>>(W, Wb);
  gemm_sig<<<(TOKENS / BM) * (DOUT / BN), 512, 0, stream>>>(xn, Wb, out);
}